// Round 6
// baseline (91.911 us; speedup 1.0000x reference)
//
#include <hip/hip_runtime.h>
#include <math.h>

#define N_ 2048
#define K_ 512
#define J_ 256
#define NR 4      // n rows per block

typedef __attribute__((address_space(3))) float       lds_f;
typedef const __attribute__((address_space(1))) float glb_f;

// 2 muls + 1 max3 + 1 min3 per 2 products = 2.0 VALU ops/product.
#define MAX3(acc, a, b) asm("v_max3_f32 %0, %0, %1, %2" : "+v"(acc) : "v"(a), "v"(b))
#define MIN3(acc, a, b) asm("v_min3_f32 %0, %0, %1, %2" : "+v"(acc) : "v"(a), "v"(b))

// Grid 512 x 512 threads (8 waves), 2 blocks/CU, 4 waves/SIMD.
// Wave = one 64-k chunk; lane owns j ∈ {lane, 64+lane, 128+lane, 192+lane}
// (all 256 j per wave -> each uniform x broadcast feeds 4 j: LDS cost 12.3K cyc/CU,
// under the 16.4K VALU floor). w is loaded per 8-k sub-chunk through ASM
// global_load_dwordx4 (opaque outputs -> compiler CANNOT sink/remat them, the
// R5 failure: VGPR_Count=92 proved plain-C wreg was demoted to in-loop reloads).
// No barriers in the main loop; 8-way k-split combined via LDS at the end.
__global__ __launch_bounds__(512, 4) void mam_fused7(
    const float* __restrict__ x, const float* __restrict__ w,
    const float* __restrict__ bias, float* __restrict__ out)
{
    __shared__ __align__(16) float xls[NR * 512];        // 8 KB x tile
    __shared__ __align__(16) float cmb[8 * NR * J_ * 2]; // 64 KB partials [c][n][j][mx,mn]

    const int t    = threadIdx.x;
    const int lane = t & 63;
    const int kc   = __builtin_amdgcn_readfirstlane(t >> 6);   // wave id = k-chunk 0..7
    const int n0   = (int)blockIdx.x * NR;

    // Stage x[NR][512] once: wave kc stages half-row (1 KB).
    {
        const int r = kc >> 1, h = kc & 1;
        __builtin_amdgcn_global_load_lds(
            (glb_f*)(x + (size_t)(n0 + r) * K_ + h * 256 + lane * 4),
            (lds_f*)(xls + r * 512 + h * 256), 16, 0, 0);
    }

    // Per-q w row pointers: j = q*64 + lane, k base = kc*64.
    const float* wq[4];
#pragma unroll
    for (int q = 0; q < 4; ++q)
        wq[q] = w + (size_t)(q * 64 + lane) * K_ + kc * 64;

    float mx[NR][4], mn[NR][4];
#pragma unroll
    for (int n = 0; n < NR; ++n)
#pragma unroll
        for (int q = 0; q < 4; ++q) {
            mx[n][q] = -__builtin_inff();
            mn[n][q] =  __builtin_inff();
        }

    __syncthreads();   // vmcnt(0) drain: x tile resident

    float4 wv[4][2];   // 32 VGPR live w window: 4 j x 8 k

    // Load the 8-k sub-chunk for all 4 j rows; wait in-asm (values opaque to
    // the compiler -> guaranteed VGPR-resident, no remat).
#define WLOAD(S0, S1)                                                         \
    asm volatile(                                                             \
        "global_load_dwordx4 %0, %8, off offset:" S0 "\n\t"                   \
        "global_load_dwordx4 %1, %8, off offset:" S1 "\n\t"                   \
        "global_load_dwordx4 %2, %9, off offset:" S0 "\n\t"                   \
        "global_load_dwordx4 %3, %9, off offset:" S1 "\n\t"                   \
        "global_load_dwordx4 %4, %10, off offset:" S0 "\n\t"                  \
        "global_load_dwordx4 %5, %10, off offset:" S1 "\n\t"                  \
        "global_load_dwordx4 %6, %11, off offset:" S0 "\n\t"                  \
        "global_load_dwordx4 %7, %11, off offset:" S1 "\n\t"                  \
        "s_waitcnt vmcnt(0)"                                                  \
        : "=&v"(wv[0][0]), "=&v"(wv[0][1]), "=&v"(wv[1][0]), "=&v"(wv[1][1]), \
          "=&v"(wv[2][0]), "=&v"(wv[2][1]), "=&v"(wv[3][0]), "=&v"(wv[3][1])  \
        : "v"(wq[0]), "v"(wq[1]), "v"(wq[2]), "v"(wq[3]))

    // Compute one 8-k sub-chunk: per n, 2 uniform ds_read_b128 broadcasts
    // + 4q x (8 mul + 4 max3 + 4 min3).
#define CSUB(S)                                                               \
    _Pragma("unroll")                                                         \
    for (int n = 0; n < NR; ++n) {                                            \
        const float4 x0 = *(const float4*)&xls[n * 512 + kc * 64 + (S) * 8];  \
        const float4 x1 = *(const float4*)&xls[n * 512 + kc * 64 + (S) * 8 + 4]; \
        _Pragma("unroll")                                                     \
        for (int q = 0; q < 4; ++q) {                                         \
            const float4 a0 = wv[q][0], a1 = wv[q][1];                        \
            const float p0 = x0.x * a0.x, p1 = x0.y * a0.y;                   \
            const float p2 = x0.z * a0.z, p3 = x0.w * a0.w;                   \
            const float p4 = x1.x * a1.x, p5 = x1.y * a1.y;                   \
            const float p6 = x1.z * a1.z, p7 = x1.w * a1.w;                   \
            MAX3(mx[n][q], p0, p1); MAX3(mx[n][q], p2, p3);                   \
            MAX3(mx[n][q], p4, p5); MAX3(mx[n][q], p6, p7);                   \
            MIN3(mn[n][q], p0, p1); MIN3(mn[n][q], p2, p3);                   \
            MIN3(mn[n][q], p4, p5); MIN3(mn[n][q], p6, p7);                   \
        }                                                                     \
    }

    WLOAD(  "0",  "16"); CSUB(0);
    WLOAD( "32",  "48"); CSUB(1);
    WLOAD( "64",  "80"); CSUB(2);
    WLOAD( "96", "112"); CSUB(3);
    WLOAD("128", "144"); CSUB(4);
    WLOAD("160", "176"); CSUB(5);
    WLOAD("192", "208"); CSUB(6);
    WLOAD("224", "240"); CSUB(7);

#undef WLOAD
#undef CSUB

    // Dump per-chunk partials (disjoint slices; j = q*64+lane -> 8B stride, 2-way free).
#pragma unroll
    for (int n = 0; n < NR; ++n)
#pragma unroll
        for (int q = 0; q < 4; ++q) {
            float2 v; v.x = mx[n][q]; v.y = mn[n][q];
            *(float2*)&cmb[((kc * NR + n) * J_ + q * 64 + lane) * 2] = v;
        }
    __syncthreads();

    // Merge 8 k-chunks: 1024 outputs, 512 threads x 2, coalesced store.
#pragma unroll
    for (int i = 0; i < 2; ++i) {
        const int u = t + i * 512;
        const int n = u >> 8;
        const int j = u & 255;
        float a = -__builtin_inff(), b = __builtin_inff();
#pragma unroll
        for (int c = 0; c < 8; ++c) {
            const float2 p = *(const float2*)&cmb[((c * NR + n) * J_ + j) * 2];
            a = fmaxf(a, p.x);
            b = fminf(b, p.y);
        }
        out[(size_t)(n0 + n) * J_ + j] = a + b + bias[j];
    }
}

extern "C" void kernel_launch(void* const* d_in, const int* in_sizes, int n_in,
                              void* d_out, int out_size, void* d_ws, size_t ws_size,
                              hipStream_t stream) {
    const float* x    = (const float*)d_in[0];
    const float* w    = (const float*)d_in[1];
    const float* bias = (const float*)d_in[2];
    float* out = (float*)d_out;

    dim3 grid(N_ / NR);   // 512 n-groups
    mam_fused7<<<grid, 512, 0, stream>>>(x, w, bias, out);
}

// Round 7
// 72.692 us; speedup vs baseline: 1.2644x; 1.2644x over previous
//
#include <hip/hip_runtime.h>
#include <math.h>

#define N_ 2048
#define K_ 512
#define J_ 256

typedef float f32x4 __attribute__((ext_vector_type(4)));
typedef float f32x2 __attribute__((ext_vector_type(2)));
typedef __attribute__((address_space(3))) float  lds_f;
typedef __attribute__((address_space(3))) f32x4  lds_f4;

// 2 muls + 1 max3 + 1 min3 per 2 products = 2.0 VALU ops/product.
#define MAX3(acc, a, b) asm("v_max3_f32 %0, %0, %1, %2" : "+v"(acc) : "v"(a), "v"(b))
#define MIN3(acc, a, b) asm("v_min3_f32 %0, %0, %1, %2" : "+v"(acc) : "v"(a), "v"(b))

// Grid 1024 x 256 thr (4 waves), 4 blocks/CU, 16 waves/CU (4/SIMD).
// Block tile 64n x 8j; wave ks owns k-quarter [ks*128,+128) in 4 chunks of 32.
// Lane (rg=lane>>2, cg=lane&3): rows n0 + rg + 16i (i<4), cols j0 + cg*2+jj (jj<2)
// -> per-quad 6 LDS reads feed 64 VALU insts (1.33x headroom at 4cyc/LDS-instr).
// BOTH operands staged coalesced to LDS (R6 failure: per-lane 2KB-stride VMEM =
// 64 lines/instr = ~20us of TA serialization). Staging is reg-mediated via ASM
// loads (cannot be sunk: R5 failure) into PRIVATE per-wave LDS slices -> NO
// barriers in the main loop (per-wave vmcnt only; DS in-order per wave).
// Padding: x row-pairs pitch 68 floats, w rows pitch 36 -> 2-way max on reads.
__global__ __launch_bounds__(256, 4) void mam_fused8(
    const float* __restrict__ x, const float* __restrict__ w,
    const float* __restrict__ bias, float* __restrict__ out)
{
    __shared__ __align__(16) float sm[9856];   // 4x2176 (x) + 4x288 (w) = 39,424 B

    const int t    = threadIdx.x;
    const int lane = t & 63;
    const int ks   = __builtin_amdgcn_readfirstlane(t >> 6);   // k-quarter 0..3

    // XCD-chunked bijective swizzle (1024 = 8 * 128).
    const int wg0 = (int)blockIdx.x;
    const int wg  = (wg0 & 7) * 128 + (wg0 >> 3);
    const int bx  = wg & 31;            // j-block (8 cols)
    const int by  = wg >> 5;            // n-block (64 rows)
    const int j0  = bx * 8;
    const int n0  = by * 64;

    const int rg = lane >> 2;           // 0..15
    const int cg = lane & 3;            // 0..3

    const int XB = ks * 2176;           // wave's x slice base (floats)
    const int WB = 8704 + ks * 288;     // wave's w slice base (floats)

    // Uniform global bases (SGPR) for this wave's k-quarter.
    const float* xsb = x + (size_t)n0 * K_ + ks * 128;
    const float* wsb = w + (size_t)j0 * K_ + ks * 128;

    // Per-lane voffsets: piece (m,lane): x row = m*8 + (lane>>3), 16B col = lane&7.
    unsigned vxo[8];
#pragma unroll
    for (int m = 0; m < 8; ++m)
        vxo[m] = (unsigned)((lane >> 3) * 2048 + (lane & 7) * 16 + m * 16384);
    const unsigned vwo = (unsigned)((lane >> 3) * 2048 + (lane & 7) * 16);

    // LDS write pointers (AS3). x row r at pair (r>>1)*68 + (r&1)*32 floats.
    lds_f* xwp = (lds_f*)&sm[XB] + (lane >> 4) * 68 + ((lane >> 3) & 1) * 32 + (lane & 7) * 4;
    lds_f* wwp = (lds_f*)&sm[WB] + (lane >> 3) * 36 + (lane & 7) * 4;

    float mx[4][2], mn[4][2];
#pragma unroll
    for (int i = 0; i < 4; ++i)
#pragma unroll
        for (int jj = 0; jj < 2; ++jj) {
            mx[i][jj] = -__builtin_inff();
            mn[i][jj] =  __builtin_inff();
        }

    f32x4 px[8], pw;

    // Issue the 9 coalesced staging loads for chunk at byte offset OFS (c*128).
    // ASM: opaque outputs -> guaranteed issued here, kept in VGPRs.
#define LOADS(OFS)                                                            \
    asm volatile(                                                             \
        "global_load_dwordx4 %0, %9, %17 offset:" OFS "\n\t"                  \
        "global_load_dwordx4 %1, %10, %17 offset:" OFS "\n\t"                 \
        "global_load_dwordx4 %2, %11, %17 offset:" OFS "\n\t"                 \
        "global_load_dwordx4 %3, %12, %17 offset:" OFS "\n\t"                 \
        "global_load_dwordx4 %4, %13, %17 offset:" OFS "\n\t"                 \
        "global_load_dwordx4 %5, %14, %17 offset:" OFS "\n\t"                 \
        "global_load_dwordx4 %6, %15, %17 offset:" OFS "\n\t"                 \
        "global_load_dwordx4 %7, %16, %17 offset:" OFS "\n\t"                 \
        "global_load_dwordx4 %8, %18, %19 offset:" OFS                        \
        : "=&v"(px[0]), "=&v"(px[1]), "=&v"(px[2]), "=&v"(px[3]),             \
          "=&v"(px[4]), "=&v"(px[5]), "=&v"(px[6]), "=&v"(px[7]), "=&v"(pw)   \
        : "v"(vxo[0]), "v"(vxo[1]), "v"(vxo[2]), "v"(vxo[3]),                 \
          "v"(vxo[4]), "v"(vxo[5]), "v"(vxo[6]), "v"(vxo[7]),                 \
          "s"(xsb), "v"(vwo), "s"(wsb))

    // Drain the loads, write into the wave's private slice (ds_write_b128).
#define WRITES()                                                              \
    {                                                                         \
        asm volatile("s_waitcnt vmcnt(0)" ::: "memory");                      \
        _Pragma("unroll")                                                     \
        for (int m = 0; m < 8; ++m)                                           \
            *(lds_f4*)(xwp + m * 272) = px[m];                                \
        *(lds_f4*)wwp = pw;                                                   \
    }

    // One 32-k chunk: 8 quads x {6 ds_read_b128 + 64 VALU}.
#define COMPUTE()                                                             \
    _Pragma("unroll")                                                         \
    for (int q = 0; q < 8; ++q) {                                             \
        f32x4 xv[4], wv[2];                                                   \
        _Pragma("unroll")                                                     \
        for (int i = 0; i < 4; ++i)                                           \
            xv[i] = *(const f32x4*)&sm[XB + ((rg >> 1) + 8 * i) * 68          \
                                       + (rg & 1) * 32 + q * 4];              \
        _Pragma("unroll")                                                     \
        for (int jj = 0; jj < 2; ++jj)                                        \
            wv[jj] = *(const f32x4*)&sm[WB + (cg * 2 + jj) * 36 + q * 4];     \
        _Pragma("unroll")                                                     \
        for (int i = 0; i < 4; ++i)                                           \
            _Pragma("unroll")                                                 \
            for (int jj = 0; jj < 2; ++jj) {                                  \
                const f32x4 a = xv[i], b = wv[jj];                            \
                const float p0 = a.x * b.x, p1 = a.y * b.y;                   \
                const float p2 = a.z * b.z, p3 = a.w * b.w;                   \
                MAX3(mx[i][jj], p0, p1); MAX3(mx[i][jj], p2, p3);             \
                MIN3(mn[i][jj], p0, p1); MIN3(mn[i][jj], p2, p3);             \
            }                                                                 \
    }

    // Per-wave pipeline over the 4 chunks of the k-quarter. No block barriers.
    LOADS("0");   WRITES();
    LOADS("128"); COMPUTE(); WRITES();
    LOADS("256"); COMPUTE(); WRITES();
    LOADS("384"); COMPUTE(); WRITES();
    COMPUTE();

#undef LOADS
#undef WRITES
#undef COMPUTE

    // Combine the 4 k-quarters via LDS (reuses the staging region).
    __syncthreads();
#pragma unroll
    for (int i = 0; i < 4; ++i)
#pragma unroll
        for (int jj = 0; jj < 2; ++jj) {
            const int o = (rg + 16 * i) * 8 + cg * 2 + jj;
            f32x2 v; v.x = mx[i][jj]; v.y = mn[i][jj];
            *(f32x2*)&sm[(ks * 512 + o) * 2] = v;
        }
    __syncthreads();

#pragma unroll
    for (int e = 0; e < 2; ++e) {
        const int o = t + e * 256;
        float a = -__builtin_inff(), b = __builtin_inff();
#pragma unroll
        for (int s = 0; s < 4; ++s) {
            const f32x2 p = *(const f32x2*)&sm[(s * 512 + o) * 2];
            a = fmaxf(a, p.x);
            b = fminf(b, p.y);
        }
        const int r = o >> 3, c = o & 7;
        out[(size_t)(n0 + r) * J_ + j0 + c] = a + b + bias[j0 + c];
    }
}

extern "C" void kernel_launch(void* const* d_in, const int* in_sizes, int n_in,
                              void* d_out, int out_size, void* d_ws, size_t ws_size,
                              hipStream_t stream) {
    const float* x    = (const float*)d_in[0];
    const float* w    = (const float*)d_in[1];
    const float* bias = (const float*)d_in[2];
    float* out = (float*)d_out;

    dim3 grid(1024);   // 32 n-blocks x 32 j-blocks, XCD-swizzled in-kernel
    mam_fused8<<<grid, 256, 0, stream>>>(x, w, bias, out);
}